// Round 1
// baseline (95.409 us; speedup 1.0000x reference)
//
#include <hip/hip_runtime.h>

// Problem: features (B=16, C=256, H=64, W=64) fp32.
// Per pixel: channel stats (rms-mag, unbiased var, std), clip to [0,1],
// then 3->16->1 MLP with relu+sigmoid. Output (B,H,W) fp32.
//
// Strategy: memory-bound (64 MiB read). One block per (b,h) row.
// 256 threads = 16 w4-lanes (float4 over w => 4 pixels/thread) x 16 c-groups
// (16 channels each). float4 loads are coalesced: for a fixed channel, the
// 16 w4 lanes cover 256 contiguous bytes. LDS reduction across c-groups,
// then 64 threads finalize stats + MLP per pixel.

#define C_DIM 256
#define HW4   1024   // H*W/4 = plane stride in float4

__global__ __launch_bounds__(256) void fis_importance_kernel(
    const float* __restrict__ features,
    const float* __restrict__ W1,   // (3,16) row-major: W1[i*16+o]
    const float* __restrict__ b1,   // (16,)
    const float* __restrict__ W2,   // (16,1): W2[k]
    const float* __restrict__ b2,   // (1,)
    float* __restrict__ out)        // (B,H,W) flat
{
    const int row = blockIdx.x;          // 0..B*H-1  (= b*64 + h)
    const int tid = threadIdx.x;         // 0..255
    const int w4  = tid & 15;            // float4 index along W
    const int cg  = tid >> 4;            // channel group 0..15

    const int b = row >> 6;
    const int h = row & 63;

    // base float4 pointer for (b, c = cg*16, h, w = w4*4)
    const float4* fptr = reinterpret_cast<const float4*>(features)
        + ((size_t)(b * C_DIM + cg * 16) * 64 + h) * 16 + w4;

    float4 s = make_float4(0.f, 0.f, 0.f, 0.f);   // sum
    float4 q = make_float4(0.f, 0.f, 0.f, 0.f);   // sum of squares
#pragma unroll
    for (int i = 0; i < 16; ++i) {
        float4 v = fptr[(size_t)i * HW4];         // next channel plane
        s.x += v.x; s.y += v.y; s.z += v.z; s.w += v.w;
        q.x += v.x * v.x; q.y += v.y * v.y; q.z += v.z * v.z; q.w += v.w * v.w;
    }

    __shared__ float4 s_sum[16][16];  // [cg][w4]
    __shared__ float4 s_sq [16][16];
    s_sum[cg][w4] = s;
    s_sq [cg][w4] = q;
    __syncthreads();

    if (tid < 64) {
        const int w   = tid;          // pixel within row
        const int ww4 = w >> 2;
        const int j   = w & 3;

        float sum = 0.f, sq = 0.f;
#pragma unroll
        for (int g = 0; g < 16; ++g) {
            // threads 0..63 read consecutive floats for fixed g: conflict-free
            sum += reinterpret_cast<const float*>(&s_sum[g][ww4])[j];
            sq  += reinterpret_cast<const float*>(&s_sq [g][ww4])[j];
        }

        const float inv_c  = 1.0f / 256.0f;
        const float inv_c1 = 1.0f / 255.0f;

        float mag = sqrtf(sq * inv_c);                       // ||f||/sqrt(C)
        float var = (sq - sum * sum * inv_c) * inv_c1;       // unbiased
        var = fmaxf(var, 0.f);
        float stdv = sqrtf(var);

        mag = fminf(fmaxf(mag, 0.f), 1.f);
        float varc = fminf(var,  1.f);
        float grad = fminf(stdv, 1.f);

        // MLP: h = relu(x @ W1 + b1); out = sigmoid(h @ W2 + b2)
        float o = b2[0];
#pragma unroll
        for (int k = 0; k < 16; ++k) {
            float hk = b1[k] + mag * W1[k] + varc * W1[16 + k] + grad * W1[32 + k];
            hk = fmaxf(hk, 0.f);
            o += hk * W2[k];
        }
        out[row * 64 + w] = 1.f / (1.f + __expf(-o));
    }
}

extern "C" void kernel_launch(void* const* d_in, const int* in_sizes, int n_in,
                              void* d_out, int out_size, void* d_ws, size_t ws_size,
                              hipStream_t stream) {
    const float* features = (const float*)d_in[0];
    const float* W1 = (const float*)d_in[1];
    const float* b1 = (const float*)d_in[2];
    const float* W2 = (const float*)d_in[3];
    const float* b2 = (const float*)d_in[4];
    float* out = (float*)d_out;

    // grid = B*H = 16*64 = 1024 row-blocks
    fis_importance_kernel<<<1024, 256, 0, stream>>>(features, W1, b1, W2, b2, out);
}